// Round 7
// baseline (386.131 us; speedup 1.0000x reference)
//
#include <hip/hip_runtime.h>
#include <math.h>

#define IN_DIM 128
#define HEADS 8
#define HID 16
#define OUT_DIM 40
#define NEG 0.2f

typedef short bf16x8 __attribute__((ext_vector_type(8)));
typedef float f32x4 __attribute__((ext_vector_type(4)));

__device__ __forceinline__ unsigned short f32_to_bf16_rne(float v) {
  unsigned u = __float_as_uint(v);
  return (unsigned short)((u + 0x7FFFu + ((u >> 16) & 1u)) >> 16);
}

// ---------------- CSR build ----------------

__global__ void hist_k(const int* __restrict__ ei, int E0, int N, int* __restrict__ deg) {
  int e = blockIdx.x * blockDim.x + threadIdx.x;
  int EP = E0 + N;
  if (e >= EP) return;
  int d = (e < E0) ? ei[E0 + e] : (e - E0);
  atomicAdd(&deg[d], 1);
}

__global__ __launch_bounds__(1024) void scanA_k(const int* __restrict__ deg, int* __restrict__ rp,
                                                int* __restrict__ bsum, int n) {
  __shared__ int wsum[16];
  int tid = threadIdx.x;
  int i = blockIdx.x * 1024 + tid;
  int lane = tid & 63, w = tid >> 6;
  int v = (i < n) ? deg[i] : 0;
  int x = v;
  #pragma unroll
  for (int off = 1; off < 64; off <<= 1) {
    int y = __shfl_up(x, off);
    if (lane >= off) x += y;
  }
  if (lane == 63) wsum[w] = x;
  __syncthreads();
  if (tid < 16) {
    int s = wsum[tid];
    #pragma unroll
    for (int off = 1; off < 16; off <<= 1) {
      int y = __shfl_up(s, off);
      if (tid >= off) s += y;
    }
    wsum[tid] = s;
  }
  __syncthreads();
  int woff = (w == 0) ? 0 : wsum[w - 1];
  if (i < n) rp[i] = woff + x - v;
  if (tid == 0) bsum[blockIdx.x] = wsum[15];
}

__global__ __launch_bounds__(1024) void scanB_k(int* __restrict__ bsum, int nb,
                                                int* __restrict__ rp, int n) {
  __shared__ int wsum[16];
  int tid = threadIdx.x;
  int lane = tid & 63, w = tid >> 6;
  int v = (tid < nb) ? bsum[tid] : 0;
  int x = v;
  #pragma unroll
  for (int off = 1; off < 64; off <<= 1) {
    int y = __shfl_up(x, off);
    if (lane >= off) x += y;
  }
  if (lane == 63) wsum[w] = x;
  __syncthreads();
  if (tid < 16) {
    int s = wsum[tid];
    #pragma unroll
    for (int off = 1; off < 16; off <<= 1) {
      int y = __shfl_up(s, off);
      if (tid >= off) s += y;
    }
    wsum[tid] = s;
  }
  __syncthreads();
  int woff = (w == 0) ? 0 : wsum[w - 1];
  if (tid < nb) bsum[tid] = woff + x - v;
  if (tid == 0) rp[n] = wsum[15];
}

__global__ __launch_bounds__(1024) void scanC_k(int* __restrict__ rp, const int* __restrict__ bsum,
                                                int* __restrict__ cnt, int n) {
  int i = blockIdx.x * 1024 + threadIdx.x;
  if (i < n) {
    int v = rp[i] + bsum[blockIdx.x];
    rp[i] = v;
    cnt[i] = v;
  }
}

__global__ void scatter_k(const int* __restrict__ ei, int E0, int N,
                          int* __restrict__ cnt, int* __restrict__ csr_src) {
  int e = blockIdx.x * blockDim.x + threadIdx.x;
  int EP = E0 + N;
  if (e >= EP) return;
  int s, d;
  if (e < E0) { s = ei[e]; d = ei[E0 + e]; } else { s = e - E0; d = s; }
  int pos = atomicAdd(&cnt[d], 1);
  csr_src[pos] = s;
}

// ---------------- prep: zero deg + pack W1 (hi/lo bf16 B-frags) + W2T with folded att cols ----------------
// W1 pack: packed[((ct*4+kc)*64+lane)*8+j] = W[kc*32+(lane>>4)*8+j][ct*16+(lane&15)]; ct 8 = att dots.
// W2T: [c][k], c<40 = W2[k][c]; c=40 = sum_d W2[k][d]*as2[d]; c=41 = ad2 fold.
__global__ void prep_k(const float* __restrict__ W1, const float* __restrict__ as1,
                       const float* __restrict__ ad1, const float* __restrict__ W2,
                       const float* __restrict__ as2, const float* __restrict__ ad2,
                       unsigned short* __restrict__ whi, unsigned short* __restrict__ wlo,
                       float* __restrict__ W2T, int* __restrict__ deg, int N) {
  int t = blockIdx.x * 256 + threadIdx.x;
  if (t < N) deg[t] = 0;
  if (t < 18432) {
    int j = t & 7, lane = (t >> 3) & 63, kc = (t >> 9) & 3, ct = t >> 11;
    int k = kc * 32 + (lane >> 4) * 8 + j;
    int col = lane & 15;
    float v;
    if (ct < 8) {
      v = W1[k * 128 + ct * 16 + col];
    } else {
      int h = col & 7;
      const float* att = (col < 8) ? as1 : ad1;
      float s = 0.f;
      #pragma unroll
      for (int d = 0; d < 16; ++d) s += W1[k * 128 + h * 16 + d] * att[h * 16 + d];
      v = s;
    }
    unsigned u = __float_as_uint(v);
    unsigned hi = (u + 0x7FFFu + ((u >> 16) & 1u)) >> 16;
    float rem = v - __uint_as_float(hi << 16);
    unsigned ur = __float_as_uint(rem);
    unsigned lo = (ur + 0x7FFFu + ((ur >> 16) & 1u)) >> 16;
    whi[t] = (unsigned short)hi;
    wlo[t] = (unsigned short)lo;
  } else if (t < 18432 + 42 * 128) {
    int t2 = t - 18432;
    int c = t2 >> 7, k = t2 & 127;
    float v;
    if (c < OUT_DIM) {
      v = W2[k * OUT_DIM + c];
    } else {
      const float* att = (c == OUT_DIM) ? as2 : ad2;
      float s = 0.f;
      #pragma unroll 8
      for (int d = 0; d < OUT_DIM; ++d) s += W2[k * OUT_DIM + d] * att[d];
      v = s;
    }
    W2T[c * 128 + k] = v;
  }
}

// ---------------- GEMM1 via MFMA (split-bf16), fused a1s/a1d; h1 stored bf16 ----------------
__global__ __launch_bounds__(256) void gemm1_mfma_k(
    const float* __restrict__ x, const unsigned short* __restrict__ whi,
    const unsigned short* __restrict__ wlo,
    unsigned short* __restrict__ h1, float* __restrict__ a1s, float* __restrict__ a1d, int N) {
  int w = threadIdx.x >> 6, lane = threadIdx.x & 63;
  int quad = lane >> 4, l15 = lane & 15;
  int row = blockIdx.x * 64 + w * 16 + l15;
  int rowc = (row < N) ? row : (N - 1);

  f32x4 acc[9];
  #pragma unroll
  for (int t = 0; t < 9; ++t) acc[t] = (f32x4){0.f, 0.f, 0.f, 0.f};

  const float* xr = x + (size_t)rowc * 128 + quad * 8;
  #pragma unroll
  for (int kc = 0; kc < 4; ++kc) {
    f32x4 a0 = *reinterpret_cast<const f32x4*>(xr + kc * 32);
    f32x4 a1 = *reinterpret_cast<const f32x4*>(xr + kc * 32 + 4);
    float av[8] = {a0.x, a0.y, a0.z, a0.w, a1.x, a1.y, a1.z, a1.w};
    bf16x8 ahi, alo;
    #pragma unroll
    for (int j = 0; j < 8; ++j) {
      unsigned u = __float_as_uint(av[j]);
      unsigned hi = (u + 0x7FFFu + ((u >> 16) & 1u)) >> 16;
      float rem = av[j] - __uint_as_float(hi << 16);
      unsigned ur = __float_as_uint(rem);
      unsigned lo = (ur + 0x7FFFu + ((ur >> 16) & 1u)) >> 16;
      ahi[j] = (short)hi;
      alo[j] = (short)lo;
    }
    #pragma unroll
    for (int ct = 0; ct < 9; ++ct) {
      bf16x8 bh = *reinterpret_cast<const bf16x8*>(whi + ((size_t)(ct * 4 + kc) * 64 + lane) * 8);
      bf16x8 bl = *reinterpret_cast<const bf16x8*>(wlo + ((size_t)(ct * 4 + kc) * 64 + lane) * 8);
      acc[ct] = __builtin_amdgcn_mfma_f32_16x16x32_bf16(ahi, bh, acc[ct], 0, 0, 0);
      acc[ct] = __builtin_amdgcn_mfma_f32_16x16x32_bf16(ahi, bl, acc[ct], 0, 0, 0);
      acc[ct] = __builtin_amdgcn_mfma_f32_16x16x32_bf16(alo, bh, acc[ct], 0, 0, 0);
    }
  }
  int rbase = blockIdx.x * 64 + w * 16 + quad * 4;
  #pragma unroll
  for (int reg = 0; reg < 4; ++reg) {
    int r = rbase + reg;
    if (r < N) {
      #pragma unroll
      for (int ct = 0; ct < 8; ++ct)
        h1[(size_t)r * 128 + ct * 16 + l15] = f32_to_bf16_rne(acc[ct][reg]);
      float v = acc[8][reg];
      if (l15 < 8) a1s[r * 8 + l15] = v;
      else         a1d[r * 8 + (l15 - 8)] = v;
    }
  }
}

// ---------------- Layer-1 aggregation: wave-per-node, scalar-addressed gathers ----------------
// rs/re forced to SGPR -> csr_src[i] is a scalar load, s becomes SGPR, gathers use saddr form.
__global__ __launch_bounds__(256) void agg1_k(
    const int* __restrict__ row_ptr, const int* __restrict__ csr_src,
    const float* __restrict__ a1s, const float* __restrict__ a1d,
    const unsigned* __restrict__ h1u, const float* __restrict__ bias1,
    const float* __restrict__ W2T,
    unsigned short* __restrict__ h2, float* __restrict__ a2s, float* __restrict__ a2d, int N) {
  int wid = threadIdx.x >> 6;
  int lane = threadIdx.x & 63;
  int n = blockIdx.x * 4 + wid;
  if (n >= N) return;

  __shared__ float vrow_s[4][128];
  float* vrow = vrow_s[wid];

  int rs = __builtin_amdgcn_readfirstlane(row_ptr[n]);
  int re = __builtin_amdgcn_readfirstlane(row_ptr[n + 1]);
  int h = lane >> 3;
  float adn = a1d[n * 8 + h];

  float accx = 0.f, accy = 0.f, sw = 0.f;
  int i = rs;
  for (; i + 4 <= re; i += 4) {
    int s0 = csr_src[i], s1 = csr_src[i + 1], s2 = csr_src[i + 2], s3 = csr_src[i + 3];
    float e0 = a1s[s0 * 8 + h] + adn;
    float e1 = a1s[s1 * 8 + h] + adn;
    float e2 = a1s[s2 * 8 + h] + adn;
    float e3 = a1s[s3 * 8 + h] + adn;
    unsigned u0 = h1u[(size_t)s0 * 64 + lane];
    unsigned u1 = h1u[(size_t)s1 * 64 + lane];
    unsigned u2 = h1u[(size_t)s2 * 64 + lane];
    unsigned u3 = h1u[(size_t)s3 * 64 + lane];
    e0 = fmaxf(e0, NEG * e0);
    e1 = fmaxf(e1, NEG * e1);
    e2 = fmaxf(e2, NEG * e2);
    e3 = fmaxf(e3, NEG * e3);
    float w0 = __expf(e0), w1 = __expf(e1), w2 = __expf(e2), w3 = __expf(e3);
    sw += (w0 + w1) + (w2 + w3);
    accx += w0 * __uint_as_float(u0 << 16) + w1 * __uint_as_float(u1 << 16)
          + w2 * __uint_as_float(u2 << 16) + w3 * __uint_as_float(u3 << 16);
    accy += w0 * __uint_as_float(u0 & 0xFFFF0000u) + w1 * __uint_as_float(u1 & 0xFFFF0000u)
          + w2 * __uint_as_float(u2 & 0xFFFF0000u) + w3 * __uint_as_float(u3 & 0xFFFF0000u);
  }
  for (; i < re; ++i) {
    int s = csr_src[i];
    float e = a1s[s * 8 + h] + adn;
    e = fmaxf(e, NEG * e);
    float w = __expf(e);
    unsigned u = h1u[(size_t)s * 64 + lane];
    sw += w;
    accx += w * __uint_as_float(u << 16);
    accy += w * __uint_as_float(u & 0xFFFF0000u);
  }
  float inv = 1.f / (sw + 1e-16f);
  float2 b = *reinterpret_cast<const float2*>(bias1 + 2 * lane);
  float vx = accx * inv + b.x;
  float vy = accy * inv + b.y;
  vx = (vx > 0.f) ? vx : (__expf(vx) - 1.f);
  vy = (vy > 0.f) ? vy : (__expf(vy) - 1.f);
  vrow[2 * lane] = vx;
  vrow[2 * lane + 1] = vy;
  // same-wave LDS write->read: no barrier needed

  // fused GEMM2 row: lane c < 42 computes W2T[c] . vrow (cols 40/41 = a2s/a2d folds)
  if (lane < 42) {
    const float* wrow = W2T + lane * 128;
    float hacc = 0.f;
    #pragma unroll 8
    for (int k = 0; k < 128; k += 4) {
      float4 vk = *reinterpret_cast<const float4*>(vrow + k);
      float4 wk = *reinterpret_cast<const float4*>(wrow + k);
      hacc += vk.x * wk.x + vk.y * wk.y + vk.z * wk.z + vk.w * wk.w;
    }
    if (lane < OUT_DIM)      h2[(size_t)n * 64 + lane] = f32_to_bf16_rne(hacc);
    else if (lane == OUT_DIM) a2s[n] = hacc;
    else                      a2d[n] = hacc;
  }
}

// ---------------- Layer-2 aggregation + log_softmax: scalar-addressed, padded h2 ----------------
__global__ __launch_bounds__(256) void agg2_k(
    const int* __restrict__ row_ptr, const int* __restrict__ csr_src,
    const float* __restrict__ a2s, const float* __restrict__ a2d,
    const unsigned short* __restrict__ h2, const float* __restrict__ bias2,
    float* __restrict__ out, int N) {
  int wid = threadIdx.x >> 6;
  int lane = threadIdx.x & 63;
  int n = blockIdx.x * 4 + wid;
  if (n >= N) return;

  int rs = __builtin_amdgcn_readfirstlane(row_ptr[n]);
  int re = __builtin_amdgcn_readfirstlane(row_ptr[n + 1]);
  float adn = a2d[n];
  bool act = lane < OUT_DIM;
  float acc = 0.f, sw = 0.f;
  int i = rs;
  for (; i + 4 <= re; i += 4) {
    int s0 = csr_src[i], s1 = csr_src[i + 1], s2 = csr_src[i + 2], s3 = csr_src[i + 3];
    float e0 = a2s[s0] + adn, e1 = a2s[s1] + adn, e2 = a2s[s2] + adn, e3 = a2s[s3] + adn;
    unsigned g0 = h2[(size_t)s0 * 64 + lane];
    unsigned g1 = h2[(size_t)s1 * 64 + lane];
    unsigned g2 = h2[(size_t)s2 * 64 + lane];
    unsigned g3 = h2[(size_t)s3 * 64 + lane];
    e0 = fmaxf(e0, NEG * e0);
    e1 = fmaxf(e1, NEG * e1);
    e2 = fmaxf(e2, NEG * e2);
    e3 = fmaxf(e3, NEG * e3);
    float w0 = __expf(e0), w1 = __expf(e1), w2 = __expf(e2), w3 = __expf(e3);
    sw += (w0 + w1) + (w2 + w3);
    acc += w0 * __uint_as_float(g0 << 16) + w1 * __uint_as_float(g1 << 16)
         + w2 * __uint_as_float(g2 << 16) + w3 * __uint_as_float(g3 << 16);
  }
  for (; i < re; ++i) {
    int s = csr_src[i];
    float e = a2s[s] + adn;
    e = fmaxf(e, NEG * e);
    float w = __expf(e);
    sw += w;
    unsigned g = h2[(size_t)s * 64 + lane];
    acc += w * __uint_as_float(g << 16);
  }
  float v = act ? (acc / (sw + 1e-16f) + bias2[lane]) : -1e30f;
  float vm = v;
  #pragma unroll
  for (int off = 32; off > 0; off >>= 1) vm = fmaxf(vm, __shfl_xor(vm, off));
  float ex = act ? __expf(v - vm) : 0.f;
  float es = ex;
  #pragma unroll
  for (int off = 32; off > 0; off >>= 1) es += __shfl_xor(es, off);
  if (act) out[(size_t)n * OUT_DIM + lane] = v - vm - __logf(es);
}

// ---------------- launch ----------------

extern "C" void kernel_launch(void* const* d_in, const int* in_sizes, int n_in,
                              void* d_out, int out_size, void* d_ws, size_t ws_size,
                              hipStream_t stream) {
  const float* x   = (const float*)d_in[0];
  const float* W1  = (const float*)d_in[1];
  const float* as1 = (const float*)d_in[2];
  const float* ad1 = (const float*)d_in[3];
  const float* b1  = (const float*)d_in[4];
  const float* W2  = (const float*)d_in[5];
  const float* as2 = (const float*)d_in[6];
  const float* ad2 = (const float*)d_in[7];
  const float* b2  = (const float*)d_in[8];
  const int*   ei  = (const int*)d_in[9];
  int N  = in_sizes[0] / IN_DIM;
  int E0 = in_sizes[9] / 2;
  int EP = E0 + N;
  float* out = (float*)d_out;

  char* ws = (char*)d_ws;
  size_t off = 0;
  auto alloc = [&](size_t bytes) {
    char* p = ws + off;
    off += (bytes + 255) & ~size_t(255);
    return p;
  };
  unsigned short* h1 = (unsigned short*)alloc((size_t)N * 128 * 2);
  float* a1s  = (float*)alloc((size_t)N * 8 * 4);
  float* a1d  = (float*)alloc((size_t)N * 8 * 4);
  unsigned short* h2 = (unsigned short*)alloc((size_t)N * 64 * 2);
  float* a2s  = (float*)alloc((size_t)N * 4);
  float* a2d  = (float*)alloc((size_t)N * 4);
  int*   deg  = (int*)alloc((size_t)N * 4);
  int*   cnt  = (int*)alloc((size_t)N * 4);
  int*   rp   = (int*)alloc((size_t)(N + 4) * 4);
  int*   bsum = (int*)alloc((size_t)1024 * 4);
  int*   csr  = (int*)alloc((size_t)EP * 4);
  unsigned short* whi = (unsigned short*)alloc((size_t)9 * 4 * 64 * 8 * 2);
  unsigned short* wlo = (unsigned short*)alloc((size_t)9 * 4 * 64 * 8 * 2);
  float* W2T  = (float*)alloc((size_t)42 * 128 * 4);

  int nb = (N + 1023) / 1024;
  int prep_n = (N > 18432 + 42 * 128) ? N : (18432 + 42 * 128);
  prep_k<<<(prep_n + 255) / 256, 256, 0, stream>>>(W1, as1, ad1, W2, as2, ad2, whi, wlo, W2T, deg, N);
  hist_k<<<(EP + 255) / 256, 256, 0, stream>>>(ei, E0, N, deg);
  scanA_k<<<nb, 1024, 0, stream>>>(deg, rp, bsum, N);
  scanB_k<<<1, 1024, 0, stream>>>(bsum, nb, rp, N);
  scanC_k<<<nb, 1024, 0, stream>>>(rp, bsum, cnt, N);
  scatter_k<<<(EP + 255) / 256, 256, 0, stream>>>(ei, E0, N, cnt, csr);
  gemm1_mfma_k<<<(N + 63) / 64, 256, 0, stream>>>(x, whi, wlo, h1, a1s, a1d, N);
  agg1_k<<<(N + 3) / 4, 256, 0, stream>>>(rp, csr, a1s, a1d, (const unsigned*)h1, b1, W2T, h2, a2s, a2d, N);
  agg2_k<<<(N + 3) / 4, 256, 0, stream>>>(rp, csr, a2s, a2d, h2, b2, out, N);
}

// Round 8
// 285.974 us; speedup vs baseline: 1.3502x; 1.3502x over previous
//
#include <hip/hip_runtime.h>
#include <math.h>

#define IN_DIM 128
#define HEADS 8
#define HID 16
#define OUT_DIM 40
#define NEG 0.2f

typedef short bf16x8 __attribute__((ext_vector_type(8)));
typedef float f32x4 __attribute__((ext_vector_type(4)));

__device__ __forceinline__ unsigned short f32_to_bf16_rne(float v) {
  unsigned u = __float_as_uint(v);
  return (unsigned short)((u + 0x7FFFu + ((u >> 16) & 1u)) >> 16);
}

// ---------------- CSR build ----------------

__global__ void hist_k(const int* __restrict__ ei, int E0, int N, int* __restrict__ deg) {
  int e = blockIdx.x * blockDim.x + threadIdx.x;
  int EP = E0 + N;
  if (e >= EP) return;
  int d = (e < E0) ? ei[E0 + e] : (e - E0);
  atomicAdd(&deg[d], 1);
}

__global__ __launch_bounds__(1024) void scanA_k(const int* __restrict__ deg, int* __restrict__ rp,
                                                int* __restrict__ bsum, int n) {
  __shared__ int wsum[16];
  int tid = threadIdx.x;
  int i = blockIdx.x * 1024 + tid;
  int lane = tid & 63, w = tid >> 6;
  int v = (i < n) ? deg[i] : 0;
  int x = v;
  #pragma unroll
  for (int off = 1; off < 64; off <<= 1) {
    int y = __shfl_up(x, off);
    if (lane >= off) x += y;
  }
  if (lane == 63) wsum[w] = x;
  __syncthreads();
  if (tid < 16) {
    int s = wsum[tid];
    #pragma unroll
    for (int off = 1; off < 16; off <<= 1) {
      int y = __shfl_up(s, off);
      if (tid >= off) s += y;
    }
    wsum[tid] = s;
  }
  __syncthreads();
  int woff = (w == 0) ? 0 : wsum[w - 1];
  if (i < n) rp[i] = woff + x - v;
  if (tid == 0) bsum[blockIdx.x] = wsum[15];
}

__global__ __launch_bounds__(1024) void scanB_k(int* __restrict__ bsum, int nb,
                                                int* __restrict__ rp, int n) {
  __shared__ int wsum[16];
  int tid = threadIdx.x;
  int lane = tid & 63, w = tid >> 6;
  int v = (tid < nb) ? bsum[tid] : 0;
  int x = v;
  #pragma unroll
  for (int off = 1; off < 64; off <<= 1) {
    int y = __shfl_up(x, off);
    if (lane >= off) x += y;
  }
  if (lane == 63) wsum[w] = x;
  __syncthreads();
  if (tid < 16) {
    int s = wsum[tid];
    #pragma unroll
    for (int off = 1; off < 16; off <<= 1) {
      int y = __shfl_up(s, off);
      if (tid >= off) s += y;
    }
    wsum[tid] = s;
  }
  __syncthreads();
  int woff = (w == 0) ? 0 : wsum[w - 1];
  if (tid < nb) bsum[tid] = woff + x - v;
  if (tid == 0) rp[n] = wsum[15];
}

__global__ __launch_bounds__(1024) void scanC_k(int* __restrict__ rp, const int* __restrict__ bsum,
                                                int* __restrict__ cnt, int n) {
  int i = blockIdx.x * 1024 + threadIdx.x;
  if (i < n) {
    int v = rp[i] + bsum[blockIdx.x];
    rp[i] = v;
    cnt[i] = v;
  }
}

__global__ void scatter_k(const int* __restrict__ ei, int E0, int N,
                          int* __restrict__ cnt, int* __restrict__ csr_src) {
  int e = blockIdx.x * blockDim.x + threadIdx.x;
  int EP = E0 + N;
  if (e >= EP) return;
  int s, d;
  if (e < E0) { s = ei[e]; d = ei[E0 + e]; } else { s = e - E0; d = s; }
  int pos = atomicAdd(&cnt[d], 1);
  csr_src[pos] = s;
}

// ---------------- prep: zero deg + pack W1 (hi/lo bf16) + pack W2 (bf16, folded att cols) ----------------
// W1: packed[((ct*4+kc)*64+lane)*8+j] = W1[kc*32+(lane>>4)*8+j][ct*16+(lane&15)]; ct8 = att dots.
// W2: packed[((ct*4+kc)*64+lane)*8+j] = W2cat[k][ct*16+col]; cols 0..39=W2, 40=as2 fold, 41=ad2 fold, 42..47=0.
__global__ void prep_k(const float* __restrict__ W1, const float* __restrict__ as1,
                       const float* __restrict__ ad1, const float* __restrict__ W2,
                       const float* __restrict__ as2, const float* __restrict__ ad2,
                       unsigned short* __restrict__ whi, unsigned short* __restrict__ wlo,
                       unsigned short* __restrict__ w2p, int* __restrict__ deg, int N) {
  int t = blockIdx.x * 256 + threadIdx.x;
  if (t < N) deg[t] = 0;
  if (t < 18432) {
    int j = t & 7, lane = (t >> 3) & 63, kc = (t >> 9) & 3, ct = t >> 11;
    int k = kc * 32 + (lane >> 4) * 8 + j;
    int col = lane & 15;
    float v;
    if (ct < 8) {
      v = W1[k * 128 + ct * 16 + col];
    } else {
      int h = col & 7;
      const float* att = (col < 8) ? as1 : ad1;
      float s = 0.f;
      #pragma unroll
      for (int d = 0; d < 16; ++d) s += W1[k * 128 + h * 16 + d] * att[h * 16 + d];
      v = s;
    }
    unsigned u = __float_as_uint(v);
    unsigned hi = (u + 0x7FFFu + ((u >> 16) & 1u)) >> 16;
    float rem = v - __uint_as_float(hi << 16);
    unsigned ur = __float_as_uint(rem);
    unsigned lo = (ur + 0x7FFFu + ((ur >> 16) & 1u)) >> 16;
    whi[t] = (unsigned short)hi;
    wlo[t] = (unsigned short)lo;
  } else if (t < 18432 + 6144) {
    int u2 = t - 18432;
    int j = u2 & 7, lane = (u2 >> 3) & 63, kc = (u2 >> 9) & 3, ct = u2 >> 11;  // ct 0..2
    int k = kc * 32 + (lane >> 4) * 8 + j;
    int col = ct * 16 + (lane & 15);
    float v;
    if (col < OUT_DIM) {
      v = W2[k * OUT_DIM + col];
    } else if (col < 42) {
      const float* att = (col == OUT_DIM) ? as2 : ad2;
      float s = 0.f;
      #pragma unroll 8
      for (int d = 0; d < OUT_DIM; ++d) s += W2[k * OUT_DIM + d] * att[d];
      v = s;
    } else {
      v = 0.f;
    }
    w2p[u2] = f32_to_bf16_rne(v);
  }
}

// ---------------- GEMM1 via MFMA (split-bf16), fused a1s/a1d; h1 stored bf16 ----------------
__global__ __launch_bounds__(256) void gemm1_mfma_k(
    const float* __restrict__ x, const unsigned short* __restrict__ whi,
    const unsigned short* __restrict__ wlo,
    unsigned short* __restrict__ h1, float* __restrict__ a1s, float* __restrict__ a1d, int N) {
  int w = threadIdx.x >> 6, lane = threadIdx.x & 63;
  int quad = lane >> 4, l15 = lane & 15;
  int row = blockIdx.x * 64 + w * 16 + l15;
  int rowc = (row < N) ? row : (N - 1);

  f32x4 acc[9];
  #pragma unroll
  for (int t = 0; t < 9; ++t) acc[t] = (f32x4){0.f, 0.f, 0.f, 0.f};

  const float* xr = x + (size_t)rowc * 128 + quad * 8;
  #pragma unroll
  for (int kc = 0; kc < 4; ++kc) {
    f32x4 a0 = *reinterpret_cast<const f32x4*>(xr + kc * 32);
    f32x4 a1 = *reinterpret_cast<const f32x4*>(xr + kc * 32 + 4);
    float av[8] = {a0.x, a0.y, a0.z, a0.w, a1.x, a1.y, a1.z, a1.w};
    bf16x8 ahi, alo;
    #pragma unroll
    for (int j = 0; j < 8; ++j) {
      unsigned u = __float_as_uint(av[j]);
      unsigned hi = (u + 0x7FFFu + ((u >> 16) & 1u)) >> 16;
      float rem = av[j] - __uint_as_float(hi << 16);
      unsigned ur = __float_as_uint(rem);
      unsigned lo = (ur + 0x7FFFu + ((ur >> 16) & 1u)) >> 16;
      ahi[j] = (short)hi;
      alo[j] = (short)lo;
    }
    #pragma unroll
    for (int ct = 0; ct < 9; ++ct) {
      bf16x8 bh = *reinterpret_cast<const bf16x8*>(whi + ((size_t)(ct * 4 + kc) * 64 + lane) * 8);
      bf16x8 bl = *reinterpret_cast<const bf16x8*>(wlo + ((size_t)(ct * 4 + kc) * 64 + lane) * 8);
      acc[ct] = __builtin_amdgcn_mfma_f32_16x16x32_bf16(ahi, bh, acc[ct], 0, 0, 0);
      acc[ct] = __builtin_amdgcn_mfma_f32_16x16x32_bf16(ahi, bl, acc[ct], 0, 0, 0);
      acc[ct] = __builtin_amdgcn_mfma_f32_16x16x32_bf16(alo, bh, acc[ct], 0, 0, 0);
    }
  }
  int rbase = blockIdx.x * 64 + w * 16 + quad * 4;
  #pragma unroll
  for (int reg = 0; reg < 4; ++reg) {
    int r = rbase + reg;
    if (r < N) {
      #pragma unroll
      for (int ct = 0; ct < 8; ++ct)
        h1[(size_t)r * 128 + ct * 16 + l15] = f32_to_bf16_rne(acc[ct][reg]);
      float v = acc[8][reg];
      if (l15 < 8) a1s[r * 8 + l15] = v;
      else         a1d[r * 8 + (l15 - 8)] = v;
    }
  }
}

// ---------------- Layer-1 aggregation: wave-per-node, R5 loop structure, unroll 8 ----------------
// Epilogue = softmax-normalize + bias + ELU + packed bf16 store. GEMM2 moved to gemm2_mfma_k.
__global__ __launch_bounds__(256) void agg1_k(
    const int* __restrict__ row_ptr, const int* __restrict__ csr_src,
    const float* __restrict__ a1s, const float* __restrict__ a1d,
    const unsigned* __restrict__ h1u, const float* __restrict__ bias1,
    unsigned* __restrict__ vrowp, int N) {
  int wid = threadIdx.x >> 6;
  int lane = threadIdx.x & 63;
  int n = blockIdx.x * 4 + wid;
  if (n >= N) return;

  int rs = row_ptr[n], re = row_ptr[n + 1];
  int h = lane >> 3;
  float adn = a1d[n * 8 + h];

  float accx = 0.f, accy = 0.f, sw = 0.f;
  int i = rs;
  for (; i + 8 <= re; i += 8) {
    int s0 = csr_src[i],     s1 = csr_src[i + 1], s2 = csr_src[i + 2], s3 = csr_src[i + 3];
    int s4 = csr_src[i + 4], s5 = csr_src[i + 5], s6 = csr_src[i + 6], s7 = csr_src[i + 7];
    float e0 = a1s[s0 * 8 + h] + adn;
    float e1 = a1s[s1 * 8 + h] + adn;
    float e2 = a1s[s2 * 8 + h] + adn;
    float e3 = a1s[s3 * 8 + h] + adn;
    float e4 = a1s[s4 * 8 + h] + adn;
    float e5 = a1s[s5 * 8 + h] + adn;
    float e6 = a1s[s6 * 8 + h] + adn;
    float e7 = a1s[s7 * 8 + h] + adn;
    unsigned u0 = h1u[(size_t)s0 * 64 + lane];
    unsigned u1 = h1u[(size_t)s1 * 64 + lane];
    unsigned u2 = h1u[(size_t)s2 * 64 + lane];
    unsigned u3 = h1u[(size_t)s3 * 64 + lane];
    unsigned u4 = h1u[(size_t)s4 * 64 + lane];
    unsigned u5 = h1u[(size_t)s5 * 64 + lane];
    unsigned u6 = h1u[(size_t)s6 * 64 + lane];
    unsigned u7 = h1u[(size_t)s7 * 64 + lane];
    e0 = fmaxf(e0, NEG * e0); e1 = fmaxf(e1, NEG * e1);
    e2 = fmaxf(e2, NEG * e2); e3 = fmaxf(e3, NEG * e3);
    e4 = fmaxf(e4, NEG * e4); e5 = fmaxf(e5, NEG * e5);
    e6 = fmaxf(e6, NEG * e6); e7 = fmaxf(e7, NEG * e7);
    float w0 = __expf(e0), w1 = __expf(e1), w2 = __expf(e2), w3 = __expf(e3);
    float w4 = __expf(e4), w5 = __expf(e5), w6 = __expf(e6), w7 = __expf(e7);
    sw += ((w0 + w1) + (w2 + w3)) + ((w4 + w5) + (w6 + w7));
    accx += w0 * __uint_as_float(u0 << 16) + w1 * __uint_as_float(u1 << 16)
          + w2 * __uint_as_float(u2 << 16) + w3 * __uint_as_float(u3 << 16)
          + w4 * __uint_as_float(u4 << 16) + w5 * __uint_as_float(u5 << 16)
          + w6 * __uint_as_float(u6 << 16) + w7 * __uint_as_float(u7 << 16);
    accy += w0 * __uint_as_float(u0 & 0xFFFF0000u) + w1 * __uint_as_float(u1 & 0xFFFF0000u)
          + w2 * __uint_as_float(u2 & 0xFFFF0000u) + w3 * __uint_as_float(u3 & 0xFFFF0000u)
          + w4 * __uint_as_float(u4 & 0xFFFF0000u) + w5 * __uint_as_float(u5 & 0xFFFF0000u)
          + w6 * __uint_as_float(u6 & 0xFFFF0000u) + w7 * __uint_as_float(u7 & 0xFFFF0000u);
  }
  for (; i + 4 <= re; i += 4) {
    int s0 = csr_src[i], s1 = csr_src[i + 1], s2 = csr_src[i + 2], s3 = csr_src[i + 3];
    float e0 = a1s[s0 * 8 + h] + adn;
    float e1 = a1s[s1 * 8 + h] + adn;
    float e2 = a1s[s2 * 8 + h] + adn;
    float e3 = a1s[s3 * 8 + h] + adn;
    unsigned u0 = h1u[(size_t)s0 * 64 + lane];
    unsigned u1 = h1u[(size_t)s1 * 64 + lane];
    unsigned u2 = h1u[(size_t)s2 * 64 + lane];
    unsigned u3 = h1u[(size_t)s3 * 64 + lane];
    e0 = fmaxf(e0, NEG * e0); e1 = fmaxf(e1, NEG * e1);
    e2 = fmaxf(e2, NEG * e2); e3 = fmaxf(e3, NEG * e3);
    float w0 = __expf(e0), w1 = __expf(e1), w2 = __expf(e2), w3 = __expf(e3);
    sw += (w0 + w1) + (w2 + w3);
    accx += w0 * __uint_as_float(u0 << 16) + w1 * __uint_as_float(u1 << 16)
          + w2 * __uint_as_float(u2 << 16) + w3 * __uint_as_float(u3 << 16);
    accy += w0 * __uint_as_float(u0 & 0xFFFF0000u) + w1 * __uint_as_float(u1 & 0xFFFF0000u)
          + w2 * __uint_as_float(u2 & 0xFFFF0000u) + w3 * __uint_as_float(u3 & 0xFFFF0000u);
  }
  for (; i < re; ++i) {
    int s = csr_src[i];
    float e = a1s[s * 8 + h] + adn;
    e = fmaxf(e, NEG * e);
    float w = __expf(e);
    unsigned u = h1u[(size_t)s * 64 + lane];
    sw += w;
    accx += w * __uint_as_float(u << 16);
    accy += w * __uint_as_float(u & 0xFFFF0000u);
  }
  float inv = 1.f / (sw + 1e-16f);
  float2 b = *reinterpret_cast<const float2*>(bias1 + 2 * lane);
  float vx = accx * inv + b.x;
  float vy = accy * inv + b.y;
  vx = (vx > 0.f) ? vx : (__expf(vx) - 1.f);
  vy = (vy > 0.f) ? vy : (__expf(vy) - 1.f);
  unsigned packed = (unsigned)f32_to_bf16_rne(vx) | ((unsigned)f32_to_bf16_rne(vy) << 16);
  vrowp[(size_t)n * 64 + lane] = packed;
}

// ---------------- GEMM2 via MFMA: h2 = ELU(vrow) @ W2 (+ folded a2s/a2d cols) ----------------
__global__ __launch_bounds__(256) void gemm2_mfma_k(
    const unsigned short* __restrict__ vrow, const unsigned short* __restrict__ w2p,
    unsigned short* __restrict__ h2, float* __restrict__ a2s, float* __restrict__ a2d, int N) {
  int w = threadIdx.x >> 6, lane = threadIdx.x & 63;
  int quad = lane >> 4, l15 = lane & 15;
  int row = blockIdx.x * 64 + w * 16 + l15;
  int rowc = (row < N) ? row : (N - 1);

  f32x4 acc[3];
  #pragma unroll
  for (int t = 0; t < 3; ++t) acc[t] = (f32x4){0.f, 0.f, 0.f, 0.f};

  const unsigned short* vr = vrow + (size_t)rowc * 128 + quad * 8;
  #pragma unroll
  for (int kc = 0; kc < 4; ++kc) {
    bf16x8 a = *reinterpret_cast<const bf16x8*>(vr + kc * 32);
    #pragma unroll
    for (int ct = 0; ct < 3; ++ct) {
      bf16x8 bfrag = *reinterpret_cast<const bf16x8*>(w2p + ((size_t)(ct * 4 + kc) * 64 + lane) * 8);
      acc[ct] = __builtin_amdgcn_mfma_f32_16x16x32_bf16(a, bfrag, acc[ct], 0, 0, 0);
    }
  }
  int rbase = blockIdx.x * 64 + w * 16 + quad * 4;
  #pragma unroll
  for (int reg = 0; reg < 4; ++reg) {
    int r = rbase + reg;
    if (r < N) {
      #pragma unroll
      for (int ct = 0; ct < 3; ++ct) {
        int col = ct * 16 + l15;
        float v = acc[ct][reg];
        if (col < OUT_DIM)       h2[(size_t)r * 64 + col] = f32_to_bf16_rne(v);
        else if (col == OUT_DIM) a2s[r] = v;
        else if (col == 41)      a2d[r] = v;
      }
    }
  }
}

// ---------------- Layer-2 aggregation + log_softmax: padded h2, unroll 8 ----------------
__global__ __launch_bounds__(256) void agg2_k(
    const int* __restrict__ row_ptr, const int* __restrict__ csr_src,
    const float* __restrict__ a2s, const float* __restrict__ a2d,
    const unsigned short* __restrict__ h2, const float* __restrict__ bias2,
    float* __restrict__ out, int N) {
  int wid = threadIdx.x >> 6;
  int lane = threadIdx.x & 63;
  int n = blockIdx.x * 4 + wid;
  if (n >= N) return;

  int rs = row_ptr[n], re = row_ptr[n + 1];
  float adn = a2d[n];
  bool act = lane < OUT_DIM;
  float acc = 0.f, sw = 0.f;
  int i = rs;
  for (; i + 8 <= re; i += 8) {
    int s0 = csr_src[i],     s1 = csr_src[i + 1], s2 = csr_src[i + 2], s3 = csr_src[i + 3];
    int s4 = csr_src[i + 4], s5 = csr_src[i + 5], s6 = csr_src[i + 6], s7 = csr_src[i + 7];
    float e0 = a2s[s0] + adn, e1 = a2s[s1] + adn, e2 = a2s[s2] + adn, e3 = a2s[s3] + adn;
    float e4 = a2s[s4] + adn, e5 = a2s[s5] + adn, e6 = a2s[s6] + adn, e7 = a2s[s7] + adn;
    unsigned g0 = h2[(size_t)s0 * 64 + lane];
    unsigned g1 = h2[(size_t)s1 * 64 + lane];
    unsigned g2 = h2[(size_t)s2 * 64 + lane];
    unsigned g3 = h2[(size_t)s3 * 64 + lane];
    unsigned g4 = h2[(size_t)s4 * 64 + lane];
    unsigned g5 = h2[(size_t)s5 * 64 + lane];
    unsigned g6 = h2[(size_t)s6 * 64 + lane];
    unsigned g7 = h2[(size_t)s7 * 64 + lane];
    e0 = fmaxf(e0, NEG * e0); e1 = fmaxf(e1, NEG * e1);
    e2 = fmaxf(e2, NEG * e2); e3 = fmaxf(e3, NEG * e3);
    e4 = fmaxf(e4, NEG * e4); e5 = fmaxf(e5, NEG * e5);
    e6 = fmaxf(e6, NEG * e6); e7 = fmaxf(e7, NEG * e7);
    float w0 = __expf(e0), w1 = __expf(e1), w2 = __expf(e2), w3 = __expf(e3);
    float w4 = __expf(e4), w5 = __expf(e5), w6 = __expf(e6), w7 = __expf(e7);
    sw += ((w0 + w1) + (w2 + w3)) + ((w4 + w5) + (w6 + w7));
    acc += w0 * __uint_as_float(g0 << 16) + w1 * __uint_as_float(g1 << 16)
         + w2 * __uint_as_float(g2 << 16) + w3 * __uint_as_float(g3 << 16)
         + w4 * __uint_as_float(g4 << 16) + w5 * __uint_as_float(g5 << 16)
         + w6 * __uint_as_float(g6 << 16) + w7 * __uint_as_float(g7 << 16);
  }
  for (; i + 4 <= re; i += 4) {
    int s0 = csr_src[i], s1 = csr_src[i + 1], s2 = csr_src[i + 2], s3 = csr_src[i + 3];
    float e0 = a2s[s0] + adn, e1 = a2s[s1] + adn, e2 = a2s[s2] + adn, e3 = a2s[s3] + adn;
    unsigned g0 = h2[(size_t)s0 * 64 + lane];
    unsigned g1 = h2[(size_t)s1 * 64 + lane];
    unsigned g2 = h2[(size_t)s2 * 64 + lane];
    unsigned g3 = h2[(size_t)s3 * 64 + lane];
    e0 = fmaxf(e0, NEG * e0); e1 = fmaxf(e1, NEG * e1);
    e2 = fmaxf(e2, NEG * e2); e3 = fmaxf(e3, NEG * e3);
    float w0 = __expf(e0), w1 = __expf(e1), w2 = __expf(e2), w3 = __expf(e3);
    sw += (w0 + w1) + (w2 + w3);
    acc += w0 * __uint_as_float(g0 << 16) + w1 * __uint_as_float(g1 << 16)
         + w2 * __uint_as_float(g2 << 16) + w3 * __uint_as_float(g3 << 16);
  }
  for (; i < re; ++i) {
    int s = csr_src[i];
    float e = a2s[s] + adn;
    e = fmaxf(e, NEG * e);
    float w = __expf(e);
    sw += w;
    unsigned g = h2[(size_t)s * 64 + lane];
    acc += w * __uint_as_float(g << 16);
  }
  float v = act ? (acc / (sw + 1e-16f) + bias2[lane]) : -1e30f;
  float vm = v;
  #pragma unroll
  for (int off = 32; off > 0; off >>= 1) vm = fmaxf(vm, __shfl_xor(vm, off));
  float ex = act ? __expf(v - vm) : 0.f;
  float es = ex;
  #pragma unroll
  for (int off = 32; off > 0; off >>= 1) es += __shfl_xor(es, off);
  if (act) out[(size_t)n * OUT_DIM + lane] = v - vm - __logf(es);
}

// ---------------- launch ----------------

extern "C" void kernel_launch(void* const* d_in, const int* in_sizes, int n_in,
                              void* d_out, int out_size, void* d_ws, size_t ws_size,
                              hipStream_t stream) {
  const float* x   = (const float*)d_in[0];
  const float* W1  = (const float*)d_in[1];
  const float* as1 = (const float*)d_in[2];
  const float* ad1 = (const float*)d_in[3];
  const float* b1  = (const float*)d_in[4];
  const float* W2  = (const float*)d_in[5];
  const float* as2 = (const float*)d_in[6];
  const float* ad2 = (const float*)d_in[7];
  const float* b2  = (const float*)d_in[8];
  const int*   ei  = (const int*)d_in[9];
  int N  = in_sizes[0] / IN_DIM;
  int E0 = in_sizes[9] / 2;
  int EP = E0 + N;
  float* out = (float*)d_out;

  char* ws = (char*)d_ws;
  size_t off = 0;
  auto alloc = [&](size_t bytes) {
    char* p = ws + off;
    off += (bytes + 255) & ~size_t(255);
    return p;
  };
  unsigned short* h1   = (unsigned short*)alloc((size_t)N * 128 * 2);
  float* a1s  = (float*)alloc((size_t)N * 8 * 4);
  float* a1d  = (float*)alloc((size_t)N * 8 * 4);
  unsigned*       vrow = (unsigned*)alloc((size_t)N * 64 * 4);   // N x 128 bf16 packed
  unsigned short* h2   = (unsigned short*)alloc((size_t)N * 64 * 2);
  float* a2s  = (float*)alloc((size_t)N * 4);
  float* a2d  = (float*)alloc((size_t)N * 4);
  int*   deg  = (int*)alloc((size_t)N * 4);
  int*   cnt  = (int*)alloc((size_t)N * 4);
  int*   rp   = (int*)alloc((size_t)(N + 4) * 4);
  int*   bsum = (int*)alloc((size_t)1024 * 4);
  int*   csr  = (int*)alloc((size_t)EP * 4);
  unsigned short* whi = (unsigned short*)alloc((size_t)18432 * 2);
  unsigned short* wlo = (unsigned short*)alloc((size_t)18432 * 2);
  unsigned short* w2p = (unsigned short*)alloc((size_t)6144 * 2);

  int nb = (N + 1023) / 1024;
  prep_k<<<(N + 255) / 256, 256, 0, stream>>>(W1, as1, ad1, W2, as2, ad2, whi, wlo, w2p, deg, N);
  hist_k<<<(EP + 255) / 256, 256, 0, stream>>>(ei, E0, N, deg);
  scanA_k<<<nb, 1024, 0, stream>>>(deg, rp, bsum, N);
  scanB_k<<<1, 1024, 0, stream>>>(bsum, nb, rp, N);
  scanC_k<<<nb, 1024, 0, stream>>>(rp, bsum, cnt, N);
  scatter_k<<<(EP + 255) / 256, 256, 0, stream>>>(ei, E0, N, cnt, csr);
  gemm1_mfma_k<<<(N + 63) / 64, 256, 0, stream>>>(x, whi, wlo, h1, a1s, a1d, N);
  agg1_k<<<(N + 3) / 4, 256, 0, stream>>>(rp, csr, a1s, a1d, (const unsigned*)h1, b1, vrow, N);
  gemm2_mfma_k<<<(N + 63) / 64, 256, 0, stream>>>((const unsigned short*)vrow, w2p, h2, a2s, a2d, N);
  agg2_k<<<(N + 3) / 4, 256, 0, stream>>>(rp, csr, a2s, a2d, h2, b2, out, N);
}

// Round 9
// 266.831 us; speedup vs baseline: 1.4471x; 1.0717x over previous
//
#include <hip/hip_runtime.h>
#include <math.h>

#define IN_DIM 128
#define HEADS 8
#define HID 16
#define OUT_DIM 40
#define NEG 0.2f
#define NSLICE 8

typedef short bf16x8 __attribute__((ext_vector_type(8)));
typedef float f32x4 __attribute__((ext_vector_type(4)));

__device__ __forceinline__ unsigned short f32_to_bf16_rne(float v) {
  unsigned u = __float_as_uint(v);
  return (unsigned short)((u + 0x7FFFu + ((u >> 16) & 1u)) >> 16);
}

// ---------------- CSR build (XCD-sliced: block b -> edge chunk b>>3, dst slice b&7) ----------------

__global__ void hist_k(const int* __restrict__ ei, int E0, int N, int snode,
                       int* __restrict__ deg) {
  int b = blockIdx.x;
  int slice = b & (NSLICE - 1);
  int e = (b >> 3) * 256 + threadIdx.x;
  int EP = E0 + N;
  if (e >= EP) return;
  int d = (e < E0) ? ei[E0 + e] : (e - E0);
  if (d / snode == slice) atomicAdd(&deg[d], 1);
}

__global__ __launch_bounds__(1024) void scanA_k(const int* __restrict__ deg, int* __restrict__ rp,
                                                int* __restrict__ bsum, int n) {
  __shared__ int wsum[16];
  int tid = threadIdx.x;
  int i = blockIdx.x * 1024 + tid;
  int lane = tid & 63, w = tid >> 6;
  int v = (i < n) ? deg[i] : 0;
  int x = v;
  #pragma unroll
  for (int off = 1; off < 64; off <<= 1) {
    int y = __shfl_up(x, off);
    if (lane >= off) x += y;
  }
  if (lane == 63) wsum[w] = x;
  __syncthreads();
  if (tid < 16) {
    int s = wsum[tid];
    #pragma unroll
    for (int off = 1; off < 16; off <<= 1) {
      int y = __shfl_up(s, off);
      if (tid >= off) s += y;
    }
    wsum[tid] = s;
  }
  __syncthreads();
  int woff = (w == 0) ? 0 : wsum[w - 1];
  if (i < n) rp[i] = woff + x - v;
  if (tid == 0) bsum[blockIdx.x] = wsum[15];
}

__global__ __launch_bounds__(1024) void scanB_k(int* __restrict__ bsum, int nb,
                                                int* __restrict__ rp, int n) {
  __shared__ int wsum[16];
  int tid = threadIdx.x;
  int lane = tid & 63, w = tid >> 6;
  int v = (tid < nb) ? bsum[tid] : 0;
  int x = v;
  #pragma unroll
  for (int off = 1; off < 64; off <<= 1) {
    int y = __shfl_up(x, off);
    if (lane >= off) x += y;
  }
  if (lane == 63) wsum[w] = x;
  __syncthreads();
  if (tid < 16) {
    int s = wsum[tid];
    #pragma unroll
    for (int off = 1; off < 16; off <<= 1) {
      int y = __shfl_up(s, off);
      if (tid >= off) s += y;
    }
    wsum[tid] = s;
  }
  __syncthreads();
  int woff = (w == 0) ? 0 : wsum[w - 1];
  if (tid < nb) bsum[tid] = woff + x - v;
  if (tid == 0) rp[n] = wsum[15];
}

__global__ __launch_bounds__(1024) void scanC_k(int* __restrict__ rp, const int* __restrict__ bsum,
                                                int* __restrict__ cnt, int n) {
  int i = blockIdx.x * 1024 + threadIdx.x;
  if (i < n) {
    int v = rp[i] + bsum[blockIdx.x];
    rp[i] = v;
    cnt[i] = v;
  }
}

__global__ void scatter_k(const int* __restrict__ ei, int E0, int N, int snode,
                          int* __restrict__ cnt, int* __restrict__ csr_src) {
  int b = blockIdx.x;
  int slice = b & (NSLICE - 1);
  int e = (b >> 3) * 256 + threadIdx.x;
  int EP = E0 + N;
  if (e >= EP) return;
  int d = (e < E0) ? ei[E0 + e] : (e - E0);
  if (d / snode != slice) return;
  int s = (e < E0) ? ei[e] : d;
  int pos = atomicAdd(&cnt[d], 1);
  csr_src[pos] = s;
}

// ---------------- prep: zero deg + pack W1 (hi/lo bf16) + pack W2 (bf16, folded att cols) ----------------
__global__ void prep_k(const float* __restrict__ W1, const float* __restrict__ as1,
                       const float* __restrict__ ad1, const float* __restrict__ W2,
                       const float* __restrict__ as2, const float* __restrict__ ad2,
                       unsigned short* __restrict__ whi, unsigned short* __restrict__ wlo,
                       unsigned short* __restrict__ w2p, int* __restrict__ deg, int N) {
  int t = blockIdx.x * 256 + threadIdx.x;
  if (t < N) deg[t] = 0;
  if (t < 18432) {
    int j = t & 7, lane = (t >> 3) & 63, kc = (t >> 9) & 3, ct = t >> 11;
    int k = kc * 32 + (lane >> 4) * 8 + j;
    int col = lane & 15;
    float v;
    if (ct < 8) {
      v = W1[k * 128 + ct * 16 + col];
    } else {
      int h = col & 7;
      const float* att = (col < 8) ? as1 : ad1;
      float s = 0.f;
      #pragma unroll
      for (int d = 0; d < 16; ++d) s += W1[k * 128 + h * 16 + d] * att[h * 16 + d];
      v = s;
    }
    unsigned u = __float_as_uint(v);
    unsigned hi = (u + 0x7FFFu + ((u >> 16) & 1u)) >> 16;
    float rem = v - __uint_as_float(hi << 16);
    unsigned ur = __float_as_uint(rem);
    unsigned lo = (ur + 0x7FFFu + ((ur >> 16) & 1u)) >> 16;
    whi[t] = (unsigned short)hi;
    wlo[t] = (unsigned short)lo;
  } else if (t < 18432 + 6144) {
    int u2 = t - 18432;
    int j = u2 & 7, lane = (u2 >> 3) & 63, kc = (u2 >> 9) & 3, ct = u2 >> 11;  // ct 0..2
    int k = kc * 32 + (lane >> 4) * 8 + j;
    int col = ct * 16 + (lane & 15);
    float v;
    if (col < OUT_DIM) {
      v = W2[k * OUT_DIM + col];
    } else if (col < 42) {
      const float* att = (col == OUT_DIM) ? as2 : ad2;
      float s = 0.f;
      #pragma unroll 8
      for (int d = 0; d < OUT_DIM; ++d) s += W2[k * OUT_DIM + d] * att[d];
      v = s;
    } else {
      v = 0.f;
    }
    w2p[u2] = f32_to_bf16_rne(v);
  }
}

// ---------------- GEMM1 via MFMA (split-bf16), fused a1s/a1d; h1 stored bf16 ----------------
__global__ __launch_bounds__(256) void gemm1_mfma_k(
    const float* __restrict__ x, const unsigned short* __restrict__ whi,
    const unsigned short* __restrict__ wlo,
    unsigned short* __restrict__ h1, float* __restrict__ a1s, float* __restrict__ a1d, int N) {
  int w = threadIdx.x >> 6, lane = threadIdx.x & 63;
  int quad = lane >> 4, l15 = lane & 15;
  int row = blockIdx.x * 64 + w * 16 + l15;
  int rowc = (row < N) ? row : (N - 1);

  f32x4 acc[9];
  #pragma unroll
  for (int t = 0; t < 9; ++t) acc[t] = (f32x4){0.f, 0.f, 0.f, 0.f};

  const float* xr = x + (size_t)rowc * 128 + quad * 8;
  #pragma unroll
  for (int kc = 0; kc < 4; ++kc) {
    f32x4 a0 = *reinterpret_cast<const f32x4*>(xr + kc * 32);
    f32x4 a1 = *reinterpret_cast<const f32x4*>(xr + kc * 32 + 4);
    float av[8] = {a0.x, a0.y, a0.z, a0.w, a1.x, a1.y, a1.z, a1.w};
    bf16x8 ahi, alo;
    #pragma unroll
    for (int j = 0; j < 8; ++j) {
      unsigned u = __float_as_uint(av[j]);
      unsigned hi = (u + 0x7FFFu + ((u >> 16) & 1u)) >> 16;
      float rem = av[j] - __uint_as_float(hi << 16);
      unsigned ur = __float_as_uint(rem);
      unsigned lo = (ur + 0x7FFFu + ((ur >> 16) & 1u)) >> 16;
      ahi[j] = (short)hi;
      alo[j] = (short)lo;
    }
    #pragma unroll
    for (int ct = 0; ct < 9; ++ct) {
      bf16x8 bh = *reinterpret_cast<const bf16x8*>(whi + ((size_t)(ct * 4 + kc) * 64 + lane) * 8);
      bf16x8 bl = *reinterpret_cast<const bf16x8*>(wlo + ((size_t)(ct * 4 + kc) * 64 + lane) * 8);
      acc[ct] = __builtin_amdgcn_mfma_f32_16x16x32_bf16(ahi, bh, acc[ct], 0, 0, 0);
      acc[ct] = __builtin_amdgcn_mfma_f32_16x16x32_bf16(ahi, bl, acc[ct], 0, 0, 0);
      acc[ct] = __builtin_amdgcn_mfma_f32_16x16x32_bf16(alo, bh, acc[ct], 0, 0, 0);
    }
  }
  int rbase = blockIdx.x * 64 + w * 16 + quad * 4;
  #pragma unroll
  for (int reg = 0; reg < 4; ++reg) {
    int r = rbase + reg;
    if (r < N) {
      #pragma unroll
      for (int ct = 0; ct < 8; ++ct)
        h1[(size_t)r * 128 + ct * 16 + l15] = f32_to_bf16_rne(acc[ct][reg]);
      float v = acc[8][reg];
      if (l15 < 8) a1s[r * 8 + l15] = v;
      else         a1d[r * 8 + (l15 - 8)] = v;
    }
  }
}

// ---------------- Layer-1 aggregation: wave-per-node, unroll 8 ----------------
__global__ __launch_bounds__(256) void agg1_k(
    const int* __restrict__ row_ptr, const int* __restrict__ csr_src,
    const float* __restrict__ a1s, const float* __restrict__ a1d,
    const unsigned* __restrict__ h1u, const float* __restrict__ bias1,
    unsigned* __restrict__ vrowp, int N) {
  int wid = threadIdx.x >> 6;
  int lane = threadIdx.x & 63;
  int n = blockIdx.x * 4 + wid;
  if (n >= N) return;

  int rs = row_ptr[n], re = row_ptr[n + 1];
  int h = lane >> 3;
  float adn = a1d[n * 8 + h];

  float accx = 0.f, accy = 0.f, sw = 0.f;
  int i = rs;
  for (; i + 8 <= re; i += 8) {
    int s0 = csr_src[i],     s1 = csr_src[i + 1], s2 = csr_src[i + 2], s3 = csr_src[i + 3];
    int s4 = csr_src[i + 4], s5 = csr_src[i + 5], s6 = csr_src[i + 6], s7 = csr_src[i + 7];
    float e0 = a1s[s0 * 8 + h] + adn;
    float e1 = a1s[s1 * 8 + h] + adn;
    float e2 = a1s[s2 * 8 + h] + adn;
    float e3 = a1s[s3 * 8 + h] + adn;
    float e4 = a1s[s4 * 8 + h] + adn;
    float e5 = a1s[s5 * 8 + h] + adn;
    float e6 = a1s[s6 * 8 + h] + adn;
    float e7 = a1s[s7 * 8 + h] + adn;
    unsigned u0 = h1u[(size_t)s0 * 64 + lane];
    unsigned u1 = h1u[(size_t)s1 * 64 + lane];
    unsigned u2 = h1u[(size_t)s2 * 64 + lane];
    unsigned u3 = h1u[(size_t)s3 * 64 + lane];
    unsigned u4 = h1u[(size_t)s4 * 64 + lane];
    unsigned u5 = h1u[(size_t)s5 * 64 + lane];
    unsigned u6 = h1u[(size_t)s6 * 64 + lane];
    unsigned u7 = h1u[(size_t)s7 * 64 + lane];
    e0 = fmaxf(e0, NEG * e0); e1 = fmaxf(e1, NEG * e1);
    e2 = fmaxf(e2, NEG * e2); e3 = fmaxf(e3, NEG * e3);
    e4 = fmaxf(e4, NEG * e4); e5 = fmaxf(e5, NEG * e5);
    e6 = fmaxf(e6, NEG * e6); e7 = fmaxf(e7, NEG * e7);
    float w0 = __expf(e0), w1 = __expf(e1), w2 = __expf(e2), w3 = __expf(e3);
    float w4 = __expf(e4), w5 = __expf(e5), w6 = __expf(e6), w7 = __expf(e7);
    sw += ((w0 + w1) + (w2 + w3)) + ((w4 + w5) + (w6 + w7));
    accx += w0 * __uint_as_float(u0 << 16) + w1 * __uint_as_float(u1 << 16)
          + w2 * __uint_as_float(u2 << 16) + w3 * __uint_as_float(u3 << 16)
          + w4 * __uint_as_float(u4 << 16) + w5 * __uint_as_float(u5 << 16)
          + w6 * __uint_as_float(u6 << 16) + w7 * __uint_as_float(u7 << 16);
    accy += w0 * __uint_as_float(u0 & 0xFFFF0000u) + w1 * __uint_as_float(u1 & 0xFFFF0000u)
          + w2 * __uint_as_float(u2 & 0xFFFF0000u) + w3 * __uint_as_float(u3 & 0xFFFF0000u)
          + w4 * __uint_as_float(u4 & 0xFFFF0000u) + w5 * __uint_as_float(u5 & 0xFFFF0000u)
          + w6 * __uint_as_float(u6 & 0xFFFF0000u) + w7 * __uint_as_float(u7 & 0xFFFF0000u);
  }
  for (; i + 4 <= re; i += 4) {
    int s0 = csr_src[i], s1 = csr_src[i + 1], s2 = csr_src[i + 2], s3 = csr_src[i + 3];
    float e0 = a1s[s0 * 8 + h] + adn;
    float e1 = a1s[s1 * 8 + h] + adn;
    float e2 = a1s[s2 * 8 + h] + adn;
    float e3 = a1s[s3 * 8 + h] + adn;
    unsigned u0 = h1u[(size_t)s0 * 64 + lane];
    unsigned u1 = h1u[(size_t)s1 * 64 + lane];
    unsigned u2 = h1u[(size_t)s2 * 64 + lane];
    unsigned u3 = h1u[(size_t)s3 * 64 + lane];
    e0 = fmaxf(e0, NEG * e0); e1 = fmaxf(e1, NEG * e1);
    e2 = fmaxf(e2, NEG * e2); e3 = fmaxf(e3, NEG * e3);
    float w0 = __expf(e0), w1 = __expf(e1), w2 = __expf(e2), w3 = __expf(e3);
    sw += (w0 + w1) + (w2 + w3);
    accx += w0 * __uint_as_float(u0 << 16) + w1 * __uint_as_float(u1 << 16)
          + w2 * __uint_as_float(u2 << 16) + w3 * __uint_as_float(u3 << 16);
    accy += w0 * __uint_as_float(u0 & 0xFFFF0000u) + w1 * __uint_as_float(u1 & 0xFFFF0000u)
          + w2 * __uint_as_float(u2 & 0xFFFF0000u) + w3 * __uint_as_float(u3 & 0xFFFF0000u);
  }
  for (; i < re; ++i) {
    int s = csr_src[i];
    float e = a1s[s * 8 + h] + adn;
    e = fmaxf(e, NEG * e);
    float w = __expf(e);
    unsigned u = h1u[(size_t)s * 64 + lane];
    sw += w;
    accx += w * __uint_as_float(u << 16);
    accy += w * __uint_as_float(u & 0xFFFF0000u);
  }
  float inv = 1.f / (sw + 1e-16f);
  float2 b = *reinterpret_cast<const float2*>(bias1 + 2 * lane);
  float vx = accx * inv + b.x;
  float vy = accy * inv + b.y;
  vx = (vx > 0.f) ? vx : (__expf(vx) - 1.f);
  vy = (vy > 0.f) ? vy : (__expf(vy) - 1.f);
  unsigned packed = (unsigned)f32_to_bf16_rne(vx) | ((unsigned)f32_to_bf16_rne(vy) << 16);
  vrowp[(size_t)n * 64 + lane] = packed;
}

// ---------------- GEMM2 via MFMA: h2 = ELU(vrow) @ W2 (+ folded a2s/a2d cols) ----------------
__global__ __launch_bounds__(256) void gemm2_mfma_k(
    const unsigned short* __restrict__ vrow, const unsigned short* __restrict__ w2p,
    unsigned short* __restrict__ h2, float* __restrict__ a2s, float* __restrict__ a2d, int N) {
  int w = threadIdx.x >> 6, lane = threadIdx.x & 63;
  int quad = lane >> 4, l15 = lane & 15;
  int row = blockIdx.x * 64 + w * 16 + l15;
  int rowc = (row < N) ? row : (N - 1);

  f32x4 acc[3];
  #pragma unroll
  for (int t = 0; t < 3; ++t) acc[t] = (f32x4){0.f, 0.f, 0.f, 0.f};

  const unsigned short* vr = vrow + (size_t)rowc * 128 + quad * 8;
  #pragma unroll
  for (int kc = 0; kc < 4; ++kc) {
    bf16x8 a = *reinterpret_cast<const bf16x8*>(vr + kc * 32);
    #pragma unroll
    for (int ct = 0; ct < 3; ++ct) {
      bf16x8 bfrag = *reinterpret_cast<const bf16x8*>(w2p + ((size_t)(ct * 4 + kc) * 64 + lane) * 8);
      acc[ct] = __builtin_amdgcn_mfma_f32_16x16x32_bf16(a, bfrag, acc[ct], 0, 0, 0);
    }
  }
  int rbase = blockIdx.x * 64 + w * 16 + quad * 4;
  #pragma unroll
  for (int reg = 0; reg < 4; ++reg) {
    int r = rbase + reg;
    if (r < N) {
      #pragma unroll
      for (int ct = 0; ct < 3; ++ct) {
        int col = ct * 16 + l15;
        float v = acc[ct][reg];
        if (col < OUT_DIM)       h2[(size_t)r * 64 + col] = f32_to_bf16_rne(v);
        else if (col == OUT_DIM) a2s[r] = v;
        else if (col == 41)      a2d[r] = v;
      }
    }
  }
}

// ---------------- Layer-2 aggregation + log_softmax: padded h2, unroll 8 ----------------
__global__ __launch_bounds__(256) void agg2_k(
    const int* __restrict__ row_ptr, const int* __restrict__ csr_src,
    const float* __restrict__ a2s, const float* __restrict__ a2d,
    const unsigned short* __restrict__ h2, const float* __restrict__ bias2,
    float* __restrict__ out, int N) {
  int wid = threadIdx.x >> 6;
  int lane = threadIdx.x & 63;
  int n = blockIdx.x * 4 + wid;
  if (n >= N) return;

  int rs = row_ptr[n], re = row_ptr[n + 1];
  float adn = a2d[n];
  bool act = lane < OUT_DIM;
  float acc = 0.f, sw = 0.f;
  int i = rs;
  for (; i + 8 <= re; i += 8) {
    int s0 = csr_src[i],     s1 = csr_src[i + 1], s2 = csr_src[i + 2], s3 = csr_src[i + 3];
    int s4 = csr_src[i + 4], s5 = csr_src[i + 5], s6 = csr_src[i + 6], s7 = csr_src[i + 7];
    float e0 = a2s[s0] + adn, e1 = a2s[s1] + adn, e2 = a2s[s2] + adn, e3 = a2s[s3] + adn;
    float e4 = a2s[s4] + adn, e5 = a2s[s5] + adn, e6 = a2s[s6] + adn, e7 = a2s[s7] + adn;
    unsigned g0 = h2[(size_t)s0 * 64 + lane];
    unsigned g1 = h2[(size_t)s1 * 64 + lane];
    unsigned g2 = h2[(size_t)s2 * 64 + lane];
    unsigned g3 = h2[(size_t)s3 * 64 + lane];
    unsigned g4 = h2[(size_t)s4 * 64 + lane];
    unsigned g5 = h2[(size_t)s5 * 64 + lane];
    unsigned g6 = h2[(size_t)s6 * 64 + lane];
    unsigned g7 = h2[(size_t)s7 * 64 + lane];
    e0 = fmaxf(e0, NEG * e0); e1 = fmaxf(e1, NEG * e1);
    e2 = fmaxf(e2, NEG * e2); e3 = fmaxf(e3, NEG * e3);
    e4 = fmaxf(e4, NEG * e4); e5 = fmaxf(e5, NEG * e5);
    e6 = fmaxf(e6, NEG * e6); e7 = fmaxf(e7, NEG * e7);
    float w0 = __expf(e0), w1 = __expf(e1), w2 = __expf(e2), w3 = __expf(e3);
    float w4 = __expf(e4), w5 = __expf(e5), w6 = __expf(e6), w7 = __expf(e7);
    sw += ((w0 + w1) + (w2 + w3)) + ((w4 + w5) + (w6 + w7));
    acc += w0 * __uint_as_float(g0 << 16) + w1 * __uint_as_float(g1 << 16)
         + w2 * __uint_as_float(g2 << 16) + w3 * __uint_as_float(g3 << 16)
         + w4 * __uint_as_float(g4 << 16) + w5 * __uint_as_float(g5 << 16)
         + w6 * __uint_as_float(g6 << 16) + w7 * __uint_as_float(g7 << 16);
  }
  for (; i + 4 <= re; i += 4) {
    int s0 = csr_src[i], s1 = csr_src[i + 1], s2 = csr_src[i + 2], s3 = csr_src[i + 3];
    float e0 = a2s[s0] + adn, e1 = a2s[s1] + adn, e2 = a2s[s2] + adn, e3 = a2s[s3] + adn;
    unsigned g0 = h2[(size_t)s0 * 64 + lane];
    unsigned g1 = h2[(size_t)s1 * 64 + lane];
    unsigned g2 = h2[(size_t)s2 * 64 + lane];
    unsigned g3 = h2[(size_t)s3 * 64 + lane];
    e0 = fmaxf(e0, NEG * e0); e1 = fmaxf(e1, NEG * e1);
    e2 = fmaxf(e2, NEG * e2); e3 = fmaxf(e3, NEG * e3);
    float w0 = __expf(e0), w1 = __expf(e1), w2 = __expf(e2), w3 = __expf(e3);
    sw += (w0 + w1) + (w2 + w3);
    acc += w0 * __uint_as_float(g0 << 16) + w1 * __uint_as_float(g1 << 16)
         + w2 * __uint_as_float(g2 << 16) + w3 * __uint_as_float(g3 << 16);
  }
  for (; i < re; ++i) {
    int s = csr_src[i];
    float e = a2s[s] + adn;
    e = fmaxf(e, NEG * e);
    float w = __expf(e);
    sw += w;
    unsigned g = h2[(size_t)s * 64 + lane];
    acc += w * __uint_as_float(g << 16);
  }
  float v = act ? (acc / (sw + 1e-16f) + bias2[lane]) : -1e30f;
  float vm = v;
  #pragma unroll
  for (int off = 32; off > 0; off >>= 1) vm = fmaxf(vm, __shfl_xor(vm, off));
  float ex = act ? __expf(v - vm) : 0.f;
  float es = ex;
  #pragma unroll
  for (int off = 32; off > 0; off >>= 1) es += __shfl_xor(es, off);
  if (act) out[(size_t)n * OUT_DIM + lane] = v - vm - __logf(es);
}

// ---------------- launch ----------------

extern "C" void kernel_launch(void* const* d_in, const int* in_sizes, int n_in,
                              void* d_out, int out_size, void* d_ws, size_t ws_size,
                              hipStream_t stream) {
  const float* x   = (const float*)d_in[0];
  const float* W1  = (const float*)d_in[1];
  const float* as1 = (const float*)d_in[2];
  const float* ad1 = (const float*)d_in[3];
  const float* b1  = (const float*)d_in[4];
  const float* W2  = (const float*)d_in[5];
  const float* as2 = (const float*)d_in[6];
  const float* ad2 = (const float*)d_in[7];
  const float* b2  = (const float*)d_in[8];
  const int*   ei  = (const int*)d_in[9];
  int N  = in_sizes[0] / IN_DIM;
  int E0 = in_sizes[9] / 2;
  int EP = E0 + N;
  int snode = (N + NSLICE - 1) / NSLICE;
  float* out = (float*)d_out;

  char* ws = (char*)d_ws;
  size_t off = 0;
  auto alloc = [&](size_t bytes) {
    char* p = ws + off;
    off += (bytes + 255) & ~size_t(255);
    return p;
  };
  unsigned short* h1   = (unsigned short*)alloc((size_t)N * 128 * 2);
  float* a1s  = (float*)alloc((size_t)N * 8 * 4);
  float* a1d  = (float*)alloc((size_t)N * 8 * 4);
  unsigned*       vrow = (unsigned*)alloc((size_t)N * 64 * 4);   // N x 128 bf16 packed
  unsigned short* h2   = (unsigned short*)alloc((size_t)N * 64 * 2);
  float* a2s  = (float*)alloc((size_t)N * 4);
  float* a2d  = (float*)alloc((size_t)N * 4);
  int*   deg  = (int*)alloc((size_t)N * 4);
  int*   cnt  = (int*)alloc((size_t)N * 4);
  int*   rp   = (int*)alloc((size_t)(N + 4) * 4);
  int*   bsum = (int*)alloc((size_t)1024 * 4);
  int*   csr  = (int*)alloc((size_t)EP * 4);
  unsigned short* whi = (unsigned short*)alloc((size_t)18432 * 2);
  unsigned short* wlo = (unsigned short*)alloc((size_t)18432 * 2);
  unsigned short* w2p = (unsigned short*)alloc((size_t)6144 * 2);

  int nb = (N + 1023) / 1024;
  int nchunk = (EP + 255) / 256;
  prep_k<<<(N + 255) / 256, 256, 0, stream>>>(W1, as1, ad1, W2, as2, ad2, whi, wlo, w2p, deg, N);
  hist_k<<<nchunk * NSLICE, 256, 0, stream>>>(ei, E0, N, snode, deg);
  scanA_k<<<nb, 1024, 0, stream>>>(deg, rp, bsum, N);
  scanB_k<<<1, 1024, 0, stream>>>(bsum, nb, rp, N);
  scanC_k<<<nb, 1024, 0, stream>>>(rp, bsum, cnt, N);
  scatter_k<<<nchunk * NSLICE, 256, 0, stream>>>(ei, E0, N, snode, cnt, csr);
  gemm1_mfma_k<<<(N + 63) / 64, 256, 0, stream>>>(x, whi, wlo, h1, a1s, a1d, N);
  agg1_k<<<(N + 3) / 4, 256, 0, stream>>>(rp, csr, a1s, a1d, (const unsigned*)h1, b1, vrow, N);
  gemm2_mfma_k<<<(N + 63) / 64, 256, 0, stream>>>((const unsigned short*)vrow, w2p, h2, a2s, a2d, N);
  agg2_k<<<(N + 3) / 4, 256, 0, stream>>>(rp, csr, a2s, a2d, h2, b2, out, N);
}